// Round 1
// baseline (200.231 us; speedup 1.0000x reference)
//
#include <hip/hip_runtime.h>

#define M 64
#define FG_T 0.6f
#define BG_T 0.4f
// packed column entry: (iou_bits << 32) | ~n  — iou in [0,1] so bit pattern is
// monotone; ties in iou resolve to SMALLER n (first occurrence, matches np argmax).
// init = iou 0.0, n = 0  (matches argmax of an all-zero column = index 0)
#define INIT_PACK 0x00000000FFFFFFFFull

__device__ inline unsigned long long shfl_xor_u64(unsigned long long v, int m) {
    int lo = (int)(unsigned int)v;
    int hi = (int)(unsigned int)(v >> 32);
    lo = __shfl_xor(lo, m);
    hi = __shfl_xor(hi, m);
    return ((unsigned long long)(unsigned int)hi << 32) | (unsigned int)lo;
}

__global__ void init_col_kernel(unsigned long long* __restrict__ col, int count) {
    int i = blockIdx.x * blockDim.x + threadIdx.x;
    if (i < count) col[i] = INIT_PACK;
}

__global__ __launch_bounds__(256) void encode_kernel(
    const float* __restrict__ gt,    // [B, M, 4] xyxy
    const int*   __restrict__ lab,   // [B, M]
    const float* __restrict__ db,    // [N, 4] xywh (cx, cy, w, h)
    float* __restrict__ out_loc,     // [B, N, 4]
    float* __restrict__ out_cls,     // [B, N] (written as float)
    unsigned long long* __restrict__ col, // [B, M] packed column max
    int N)
{
#pragma clang fp contract(off)
    __shared__ float4 s_gt[M];
    __shared__ float  s_area[M];
    __shared__ int    s_lab[M];
    __shared__ unsigned long long s_col[M];

    const int b   = blockIdx.y;
    const int tid = threadIdx.x;

    if (tid < M) {
        float4 g = ((const float4*)gt)[b * M + tid];
        s_gt[tid]   = g;
        s_area[tid] = (g.z - g.x) * (g.w - g.y);   // same op order as reference
        s_lab[tid]  = lab[b * M + tid];
        s_col[tid]  = INIT_PACK;
    }
    __syncthreads();

    const int  n     = blockIdx.x * 256 + tid;
    const bool valid = (n < N);
    const int  nl    = valid ? n : (N - 1);

    const float4 d = ((const float4*)db)[nl];
    // db_xyxy exactly as reference: c - wh/2, c + wh/2 (div by 2 is exact)
    const float ax0 = d.x - d.z / 2.0f;
    const float ay0 = d.y - d.w / 2.0f;
    const float ax1 = d.x + d.z / 2.0f;
    const float ay1 = d.y + d.w / 2.0f;
    const float area_a = (ax1 - ax0) * (ay1 - ay0);  // from xyxy, as reference

    float best = -1.0f;   // strict > with ascending m == np.argmax first-occurrence
    int   bi   = 0;

    for (int m = 0; m < M; ++m) {
        float4 g = s_gt[m];
        float ltx = fmaxf(ax0, g.x);
        float lty = fmaxf(ay0, g.y);
        float rbx = fminf(ax1, g.z);
        float rby = fminf(ay1, g.w);
        float w = fmaxf(rbx - ltx, 0.0f);
        float h = fmaxf(rby - lty, 0.0f);
        float inter = w * h;
        float iou = inter / ((area_a + s_area[m]) - inter);  // (aA + aB) - inter, no fma

        if (iou > best) { best = iou; bi = m; }

        // column (per-GT) max: only anchors with iou > 0 can beat the init.
        bool flag = valid && (iou > 0.0f);
        unsigned long long mask = __ballot((int)flag);
        if (mask) {  // wave-uniform branch
            unsigned long long p = flag
                ? ((((unsigned long long)__float_as_uint(iou)) << 32)
                   | (unsigned int)(~(unsigned int)n))
                : 0ull;
            #pragma unroll
            for (int off = 1; off < 64; off <<= 1) {
                unsigned long long q = shfl_xor_u64(p, off);
                if (q > p) p = q;
            }
            if ((tid & 63) == 0 && p != 0ull) atomicMax(&s_col[m], p);
        }
    }
    __syncthreads();

    if (tid < M) {
        unsigned long long p = s_col[tid];
        if (p != INIT_PACK) atomicMax(&col[b * M + tid], p);
    }

    if (valid) {
        float t = best;
        float cv;
        if (t < BG_T)      cv = 0.0f;
        else if (t < FG_T) cv = -1.0f;
        else               cv = (float)(s_lab[bi] + 1);

        float4 g = s_gt[bi];
        float bcx = (g.x + g.z) / 2.0f;
        float bcy = (g.y + g.w) / 2.0f;
        float bw  = g.z - g.x;
        float bh  = g.w - g.y;
        float lx = ((bcx - d.x) / d.z) / 0.1f;
        float ly = ((bcy - d.y) / d.w) / 0.1f;
        float lw = logf(bw / d.z) / 0.2f;
        float lh = logf(bh / d.w) / 0.2f;

        ((float4*)out_loc)[(size_t)b * N + n] = make_float4(lx, ly, lw, lh);
        out_cls[(size_t)b * N + n] = cv;
    }
}

// Apply the best_p_idx override: best_t_idx[best_p[m]] = m (last write wins),
// best_t -> 2.0 so cls = lab+1 and loc re-encoded from gt[m].
__global__ void fixup_kernel(
    const float* __restrict__ gt,
    const int*   __restrict__ lab,
    const float* __restrict__ db,
    const unsigned long long* __restrict__ col,
    float* __restrict__ out_loc,
    float* __restrict__ out_cls,
    int N)
{
#pragma clang fp contract(off)
    __shared__ int s_a[M];
    const int b = blockIdx.x;
    const int m = threadIdx.x;  // 64 threads

    unsigned long long p = col[b * M + m];
    int a = (int)(~(unsigned int)(p & 0xFFFFFFFFull));
    s_a[m] = a;
    __syncthreads();

    // last-write-wins for duplicate anchors (np fancy assignment semantics)
    bool write = true;
    for (int mm = m + 1; mm < M; ++mm) {
        if (s_a[mm] == a) { write = false; break; }
    }
    if (write) {
        float4 d = ((const float4*)db)[a];
        float4 g = ((const float4*)gt)[b * M + m];
        float bcx = (g.x + g.z) / 2.0f;
        float bcy = (g.y + g.w) / 2.0f;
        float bw  = g.z - g.x;
        float bh  = g.w - g.y;
        float lx = ((bcx - d.x) / d.z) / 0.1f;
        float ly = ((bcy - d.y) / d.w) / 0.1f;
        float lw = logf(bw / d.z) / 0.2f;
        float lh = logf(bh / d.w) / 0.2f;

        ((float4*)out_loc)[(size_t)b * N + a] = make_float4(lx, ly, lw, lh);
        out_cls[(size_t)b * N + a] = (float)(lab[b * M + m] + 1);  // best_t = 2.0 >= FG_T
    }
}

extern "C" void kernel_launch(void* const* d_in, const int* in_sizes, int n_in,
                              void* d_out, int out_size, void* d_ws, size_t ws_size,
                              hipStream_t stream) {
    const float* gt  = (const float*)d_in[0];   // gt_boxes  [B, M, 4] xyxy
    const int*   lab = (const int*)d_in[1];     // labels    [B, M]
    const float* db  = (const float*)d_in[2];   // default_boxes [N, 4] xywh

    const int B = in_sizes[1] / M;
    const int N = in_sizes[2] / 4;

    float* out_loc = (float*)d_out;                       // [B, N, 4]
    float* out_cls = out_loc + (size_t)B * N * 4;         // [B, N]

    unsigned long long* col = (unsigned long long*)d_ws;  // [B, M] — 16 KB
    const int cnt = B * M;

    init_col_kernel<<<dim3((cnt + 255) / 256), dim3(256), 0, stream>>>(col, cnt);
    encode_kernel<<<dim3((N + 255) / 256, B), dim3(256), 0, stream>>>(
        gt, lab, db, out_loc, out_cls, col, N);
    fixup_kernel<<<dim3(B), dim3(M), 0, stream>>>(gt, lab, db, col, out_loc, out_cls, N);
}

// Round 2
// 197.881 us; speedup vs baseline: 1.0119x; 1.0119x over previous
//
#include <hip/hip_runtime.h>

#define M 64
#define FG_T 0.6f
#define BG_T 0.4f
// packed column entry: (iou_bits << 32) | ~n  — iou in [0,1] so bit pattern is
// monotone; ties in iou resolve to SMALLER n (first occurrence, matches np argmax).
// init = iou 0.0, n = 0  (matches argmax of an all-zero column = index 0)
#define INIT_PACK 0x00000000FFFFFFFFull

__device__ inline unsigned long long shfl_xor_u64(unsigned long long v, int m) {
    int lo = (int)(unsigned int)v;
    int hi = (int)(unsigned int)(v >> 32);
    lo = __shfl_xor(lo, m);
    hi = __shfl_xor(hi, m);
    return ((unsigned long long)(unsigned int)hi << 32) | (unsigned int)lo;
}

__global__ void init_col_kernel(unsigned long long* __restrict__ col, int count) {
    int i = blockIdx.x * blockDim.x + threadIdx.x;
    if (i < count) col[i] = INIT_PACK;
}

__global__ __launch_bounds__(256) void encode_kernel(
    const float* __restrict__ gt,    // [B, M, 4] xyxy
    const int*   __restrict__ lab,   // [B, M]
    const float* __restrict__ db,    // [N, 4] xywh (cx, cy, w, h)
    float* __restrict__ out_loc,     // [B, N, 4]
    float* __restrict__ out_cls,     // [B, N] (written as float)
    unsigned long long* __restrict__ col, // [B, M] packed column max
    int N)
{
#pragma clang fp contract(off)
    __shared__ float s_area[M];
    __shared__ float s_colmax[M];   // running column max (float bits; monotone)
    __shared__ unsigned long long s_col[M];

    const int b   = blockIdx.y;
    const int tid = threadIdx.x;
    const float4* __restrict__ gtb = (const float4*)gt + b * M;  // block-uniform

    if (tid < M) {
        float4 g = gtb[tid];
        s_area[tid]   = (g.z - g.x) * (g.w - g.y);   // same op order as reference
        s_colmax[tid] = 0.0f;
        s_col[tid]    = INIT_PACK;
    }
    __syncthreads();

    const int  n     = blockIdx.x * 256 + tid;
    const bool valid = (n < N);
    const int  nl    = valid ? n : (N - 1);

    const float4 d = ((const float4*)db)[nl];
    // db_xyxy exactly as reference: c - wh/2, c + wh/2 (div by 2 is exact)
    const float ax0 = d.x - d.z / 2.0f;
    const float ay0 = d.y - d.w / 2.0f;
    const float ax1 = d.x + d.z / 2.0f;
    const float ay1 = d.y + d.w / 2.0f;
    const float area_a = (ax1 - ax0) * (ay1 - ay0);  // from xyxy, as reference

    float best = -1.0f;   // strict > with ascending m == np.argmax first-occurrence
    int   bi   = 0;

    #pragma unroll 4
    for (int m = 0; m < M; ++m) {
        // gtb[m] is block-uniform -> s_load_dwordx4 (scalar pipe, L1/L2 cached)
        float4 g = gtb[m];
        float ltx = fmaxf(ax0, g.x);
        float lty = fmaxf(ay0, g.y);
        float rbx = fminf(ax1, g.z);
        float rby = fminf(ay1, g.w);
        float w = fmaxf(rbx - ltx, 0.0f);
        float h = fmaxf(rby - lty, 0.0f);
        float inter = w * h;
        float iou = inter / ((area_a + s_area[m]) - inter);  // IEEE div: bit-exact vs np

        if (iou > best) { best = iou; bi = m; }

        // Opportunistic column max: only run the reduction if some lane in this
        // wave beats the block's running column max (rare: anchors are spatially
        // local, most waves never overlap GT m). Stale colmax reads are benign —
        // colmax is monotone, a low read just causes a spurious exact slow path.
        bool pass = valid && (iou > 0.0f) && (iou >= s_colmax[m]);
        if (__ballot((int)pass)) {   // wave-uniform branch; all 64 lanes active inside
            unsigned long long p = pass
                ? ((((unsigned long long)__float_as_uint(iou)) << 32)
                   | (unsigned int)(~(unsigned int)n))
                : 0ull;
            #pragma unroll
            for (int off = 1; off < 64; off <<= 1) {
                unsigned long long q = shfl_xor_u64(p, off);
                if (q > p) p = q;
            }
            if ((tid & 63) == 0 && p != 0ull) {
                atomicMax(&s_col[m], p);
                // float bits of a non-negative float compare correctly as u32
                atomicMax((unsigned int*)&s_colmax[m], (unsigned int)(p >> 32));
            }
        }
    }
    __syncthreads();

    if (tid < M) {
        unsigned long long p = s_col[tid];
        if (p != INIT_PACK) atomicMax(&col[b * M + tid], p);
    }

    if (valid) {
        float t = best;
        float cv;
        if (t < BG_T)      cv = 0.0f;
        else if (t < FG_T) cv = -1.0f;
        else               cv = (float)(lab[b * M + bi] + 1);

        float4 g = gtb[bi];
        float bcx = (g.x + g.z) / 2.0f;
        float bcy = (g.y + g.w) / 2.0f;
        float bw  = g.z - g.x;
        float bh  = g.w - g.y;
        float lx = ((bcx - d.x) / d.z) / 0.1f;
        float ly = ((bcy - d.y) / d.w) / 0.1f;
        float lw = logf(bw / d.z) / 0.2f;
        float lh = logf(bh / d.w) / 0.2f;

        ((float4*)out_loc)[(size_t)b * N + n] = make_float4(lx, ly, lw, lh);
        out_cls[(size_t)b * N + n] = cv;
    }
}

// Apply the best_p_idx override: best_t_idx[best_p[m]] = m (last write wins),
// best_t -> 2.0 so cls = lab+1 and loc re-encoded from gt[m].
__global__ void fixup_kernel(
    const float* __restrict__ gt,
    const int*   __restrict__ lab,
    const float* __restrict__ db,
    const unsigned long long* __restrict__ col,
    float* __restrict__ out_loc,
    float* __restrict__ out_cls,
    int N)
{
#pragma clang fp contract(off)
    __shared__ int s_a[M];
    const int b = blockIdx.x;
    const int m = threadIdx.x;  // 64 threads

    unsigned long long p = col[b * M + m];
    int a = (int)(~(unsigned int)(p & 0xFFFFFFFFull));
    s_a[m] = a;
    __syncthreads();

    // last-write-wins for duplicate anchors (np fancy assignment semantics)
    bool write = true;
    for (int mm = m + 1; mm < M; ++mm) {
        if (s_a[mm] == a) { write = false; break; }
    }
    if (write) {
        float4 d = ((const float4*)db)[a];
        float4 g = ((const float4*)gt)[b * M + m];
        float bcx = (g.x + g.z) / 2.0f;
        float bcy = (g.y + g.w) / 2.0f;
        float bw  = g.z - g.x;
        float bh  = g.w - g.y;
        float lx = ((bcx - d.x) / d.z) / 0.1f;
        float ly = ((bcy - d.y) / d.w) / 0.1f;
        float lw = logf(bw / d.z) / 0.2f;
        float lh = logf(bh / d.w) / 0.2f;

        ((float4*)out_loc)[(size_t)b * N + a] = make_float4(lx, ly, lw, lh);
        out_cls[(size_t)b * N + a] = (float)(lab[b * M + m] + 1);  // best_t = 2.0 >= FG_T
    }
}

extern "C" void kernel_launch(void* const* d_in, const int* in_sizes, int n_in,
                              void* d_out, int out_size, void* d_ws, size_t ws_size,
                              hipStream_t stream) {
    const float* gt  = (const float*)d_in[0];   // gt_boxes  [B, M, 4] xyxy
    const int*   lab = (const int*)d_in[1];     // labels    [B, M]
    const float* db  = (const float*)d_in[2];   // default_boxes [N, 4] xywh

    const int B = in_sizes[1] / M;
    const int N = in_sizes[2] / 4;

    float* out_loc = (float*)d_out;                       // [B, N, 4]
    float* out_cls = out_loc + (size_t)B * N * 4;         // [B, N]

    unsigned long long* col = (unsigned long long*)d_ws;  // [B, M] — 16 KB
    const int cnt = B * M;

    init_col_kernel<<<dim3((cnt + 255) / 256), dim3(256), 0, stream>>>(col, cnt);
    encode_kernel<<<dim3((N + 255) / 256, B), dim3(256), 0, stream>>>(
        gt, lab, db, out_loc, out_cls, col, N);
    fixup_kernel<<<dim3(B), dim3(M), 0, stream>>>(gt, lab, db, col, out_loc, out_cls, N);
}

// Round 3
// 181.882 us; speedup vs baseline: 1.1009x; 1.0880x over previous
//
#include <hip/hip_runtime.h>

#define M 64
#define FG_T 0.6f
#define BG_T 0.4f
// packed column entry: (iou_bits << 32) | ~n  — iou in [0,1] so bit pattern is
// monotone; ties in iou resolve to SMALLER n (first occurrence, matches np argmax).
// init = iou 0.0, n = 0  (decodes to anchor 0, matching np.argmax of all-zero col)
#define INIT_PACK 0x00000000FFFFFFFFull

__device__ inline unsigned long long shfl_xor_u64(unsigned long long v, int m) {
    int lo = (int)(unsigned int)v;
    int hi = (int)(unsigned int)(v >> 32);
    lo = __shfl_xor(lo, m);
    hi = __shfl_xor(hi, m);
    return ((unsigned long long)(unsigned int)hi << 32) | (unsigned int)lo;
}

__global__ void init_col_kernel(unsigned long long* __restrict__ col, int count) {
    int i = blockIdx.x * blockDim.x + threadIdx.x;
    if (i < count) col[i] = INIT_PACK;
}

__global__ __launch_bounds__(256) void encode_kernel(
    const float* __restrict__ gt,    // [B, M, 4] xyxy
    const int*   __restrict__ lab,   // [B, M]
    const float* __restrict__ db,    // [N, 4] xywh (cx, cy, w, h)
    float* __restrict__ out_loc,     // [B, N, 4]
    float* __restrict__ out_cls,     // [B, N] (written as float)
    unsigned long long* __restrict__ col, // [B, M] packed column max
    int N)
{
#pragma clang fp contract(off)
    __shared__ float s_area[M];
    __shared__ float s_colmax[M];   // running column max (float bits; monotone)
    __shared__ unsigned long long s_col[M];

    const int b   = blockIdx.y;
    const int tid = threadIdx.x;
    const float4* __restrict__ gtb = (const float4*)gt + b * M;  // block-uniform

    if (tid < M) {
        float4 g = gtb[tid];
        s_area[tid]   = (g.z - g.x) * (g.w - g.y);   // same op order as reference
        s_colmax[tid] = 0.0f;
        s_col[tid]    = INIT_PACK;
    }
    __syncthreads();

    const int  n     = blockIdx.x * 256 + tid;
    const bool valid = (n < N);
    const int  nl    = valid ? n : (N - 1);

    const float4 d = ((const float4*)db)[nl];
    // db_xyxy exactly as reference: c - wh/2, c + wh/2 (div by 2 is exact)
    const float ax0 = d.x - d.z / 2.0f;
    const float ay0 = d.y - d.w / 2.0f;
    const float ax1 = d.x + d.z / 2.0f;
    const float ay1 = d.y + d.w / 2.0f;
    const float area_a = (ax1 - ax0) * (ay1 - ay0);  // from xyxy, as reference

    // best=0, bi=0: a row whose ious are all exactly 0 keeps bi=0, which is
    // np.argmax(first-max) semantics; strict > gives first-occurrence otherwise.
    float best = 0.0f;
    int   bi   = 0;

    float4 gnext = gtb[0];   // software-pipelined block-uniform scalar load
    for (int m = 0; m < M; ++m) {
        float4 g = gnext;
        gnext = gtb[(m + 1) & (M - 1)];   // uniform, branch-free prefetch

        float ltx = fmaxf(ax0, g.x);
        float lty = fmaxf(ay0, g.y);
        float rbx = fminf(ax1, g.z);
        float rby = fminf(ay1, g.w);
        float w = fmaxf(rbx - ltx, 0.0f);
        float h = fmaxf(rby - lty, 0.0f);
        float inter = w * h;

        // Wave-uniform skip: ~97% of (wave, GT) pairs have no intersecting lane.
        // Inside the branch, lanes with inter==0 get iou = 0/denom = +0.0 —
        // bit-identical to the branchless version, so ordering is unaffected.
        if (__any(inter > 0.0f)) {
            float iou = inter / ((area_a + s_area[m]) - inter);  // IEEE div: bit-exact vs np

            if (iou > best) { best = iou; bi = m; }

            // Opportunistic column (per-GT) max; stale colmax reads are benign
            // (monotone — a low read only causes a spurious exact slow path).
            bool pass = valid && (iou > 0.0f) && (iou >= s_colmax[m]);
            if (__ballot((int)pass)) {   // wave-uniform; all 64 lanes active inside
                unsigned long long p = pass
                    ? ((((unsigned long long)__float_as_uint(iou)) << 32)
                       | (unsigned int)(~(unsigned int)n))
                    : 0ull;
                #pragma unroll
                for (int off = 1; off < 64; off <<= 1) {
                    unsigned long long q = shfl_xor_u64(p, off);
                    if (q > p) p = q;
                }
                if ((tid & 63) == 0 && p != 0ull) {
                    atomicMax(&s_col[m], p);
                    // float bits of a non-negative float compare correctly as u32
                    atomicMax((unsigned int*)&s_colmax[m], (unsigned int)(p >> 32));
                }
            }
        }
    }
    __syncthreads();

    if (tid < M) {
        unsigned long long p = s_col[tid];
        if (p != INIT_PACK) atomicMax(&col[b * M + tid], p);
    }

    if (valid) {
        float t = best;
        float cv;
        if (t < BG_T)      cv = 0.0f;
        else if (t < FG_T) cv = -1.0f;
        else               cv = (float)(lab[b * M + bi] + 1);

        float4 g = gtb[bi];
        float bcx = (g.x + g.z) / 2.0f;
        float bcy = (g.y + g.w) / 2.0f;
        float bw  = g.z - g.x;
        float bh  = g.w - g.y;
        float lx = ((bcx - d.x) / d.z) / 0.1f;
        float ly = ((bcy - d.y) / d.w) / 0.1f;
        float lw = __logf(bw / d.z) / 0.2f;   // ~1e-6 abs err vs 3.54 threshold
        float lh = __logf(bh / d.w) / 0.2f;

        ((float4*)out_loc)[(size_t)b * N + n] = make_float4(lx, ly, lw, lh);
        out_cls[(size_t)b * N + n] = cv;
    }
}

// Apply the best_p_idx override: best_t_idx[best_p[m]] = m (last write wins),
// best_t -> 2.0 so cls = lab+1 and loc re-encoded from gt[m].
__global__ void fixup_kernel(
    const float* __restrict__ gt,
    const int*   __restrict__ lab,
    const float* __restrict__ db,
    const unsigned long long* __restrict__ col,
    float* __restrict__ out_loc,
    float* __restrict__ out_cls,
    int N)
{
#pragma clang fp contract(off)
    __shared__ int s_a[M];
    const int b = blockIdx.x;
    const int m = threadIdx.x;  // 64 threads

    unsigned long long p = col[b * M + m];
    int a = (int)(~(unsigned int)(p & 0xFFFFFFFFull));
    s_a[m] = a;
    __syncthreads();

    // last-write-wins for duplicate anchors (np fancy assignment semantics)
    bool write = true;
    for (int mm = m + 1; mm < M; ++mm) {
        if (s_a[mm] == a) { write = false; break; }
    }
    if (write) {
        float4 d = ((const float4*)db)[a];
        float4 g = ((const float4*)gt)[b * M + m];
        float bcx = (g.x + g.z) / 2.0f;
        float bcy = (g.y + g.w) / 2.0f;
        float bw  = g.z - g.x;
        float bh  = g.w - g.y;
        float lx = ((bcx - d.x) / d.z) / 0.1f;
        float ly = ((bcy - d.y) / d.w) / 0.1f;
        float lw = __logf(bw / d.z) / 0.2f;
        float lh = __logf(bh / d.w) / 0.2f;

        ((float4*)out_loc)[(size_t)b * N + a] = make_float4(lx, ly, lw, lh);
        out_cls[(size_t)b * N + a] = (float)(lab[b * M + m] + 1);  // best_t = 2.0 >= FG_T
    }
}

extern "C" void kernel_launch(void* const* d_in, const int* in_sizes, int n_in,
                              void* d_out, int out_size, void* d_ws, size_t ws_size,
                              hipStream_t stream) {
    const float* gt  = (const float*)d_in[0];   // gt_boxes  [B, M, 4] xyxy
    const int*   lab = (const int*)d_in[1];     // labels    [B, M]
    const float* db  = (const float*)d_in[2];   // default_boxes [N, 4] xywh

    const int B = in_sizes[1] / M;
    const int N = in_sizes[2] / 4;

    float* out_loc = (float*)d_out;                       // [B, N, 4]
    float* out_cls = out_loc + (size_t)B * N * 4;         // [B, N]

    unsigned long long* col = (unsigned long long*)d_ws;  // [B, M] — 16 KB
    const int cnt = B * M;

    init_col_kernel<<<dim3((cnt + 255) / 256), dim3(256), 0, stream>>>(col, cnt);
    encode_kernel<<<dim3((N + 255) / 256, B), dim3(256), 0, stream>>>(
        gt, lab, db, out_loc, out_cls, col, N);
    fixup_kernel<<<dim3(B), dim3(M), 0, stream>>>(gt, lab, db, col, out_loc, out_cls, N);
}